// Round 3
// baseline (641.660 us; speedup 1.0000x reference)
//
#include <hip/hip_runtime.h>

// Problem dims (fixed by reference)
#define S_DIM 2048
#define B_DIM 32
#define H_DIM 1024
#define ROWS  (S_DIM * B_DIM)   // 65536 GEMM rows, row = s*32 + b

typedef __attribute__((ext_vector_type(4))) float    f32x4;
typedef __attribute__((ext_vector_type(8))) _Float16 f16x8;
typedef __attribute__((ext_vector_type(2))) __fp16   h16x2;  // cvt_pkrtz result type

// ---- helpers ----------------------------------------------------------------
__device__ __forceinline__ unsigned short f16_bits(float f) {
  union { _Float16 h; unsigned short u; } cv;
  cv.h = (_Float16)f;           // v_cvt_f16_f32, RNE
  return cv.u;
}

// tanh via one v_exp_f32
__device__ __forceinline__ float fast_tanh(float x) {
  x = fminf(15.0f, fmaxf(-15.0f, x));
  float z = __expf(-2.0f * x);
  return (1.0f - z) * __builtin_amdgcn_rcpf(1.0f + z);
}

// async global->LDS, 16B/lane. LDS dest must be wave-uniform base + lane*16.
__device__ __forceinline__ void load_lds16(const void* g, void* l) {
  __builtin_amdgcn_global_load_lds(
      (const __attribute__((address_space(1))) unsigned int*)g,
      (__attribute__((address_space(3))) unsigned int*)l, 16, 0, 0);
}

// inline-asm global load (fallback path only)
__device__ __forceinline__ f32x4 gload16(const float* p) {
  f32x4 r;
  asm volatile("global_load_dwordx4 %0, %1, off" : "=v"(r) : "v"(p) : "memory");
  return r;
}

#define PRIO1 __builtin_amdgcn_s_setprio(1)
#define PRIO0 __builtin_amdgcn_s_setprio(0)
#define SBAR  __builtin_amdgcn_sched_barrier(0)
#define BAR   __builtin_amdgcn_s_barrier
#define VMC(N) do { asm volatile("s_waitcnt vmcnt(" #N ")" ::: "memory"); \
                    __builtin_amdgcn_sched_barrier(0); } while (0)
#define LGKM0() do { asm volatile("s_waitcnt lgkmcnt(0)" ::: "memory"); \
                     __builtin_amdgcn_sched_barrier(0); } while (0)

// ---- K1 (fused prep): hidproj | packW2 | zero scores | zero ctx | enc->fp16 --
// Bp layout: [g=n/256][kt=k/64][2048 chunks of 16B]; chunk q (r=q>>3, p=q&7)
// holds W2[n=g*256+r][k = kt*64 + (p^(r&7))*8 ..+7] fp16 -- the exact linear
// image global_load_lds deposits (pre-swizzled source, linear LDS dest).
// encT16 layout (new path): [t=row/256][kt][2048 chunks], same chunk rule with
// rows r in [0,256): enc16[(t,kt,q)] = fp16(enc[t*256+r][kt*64 + (p^(r&7))*8]).
__global__ void prep_kernel(const float* __restrict__ hidden,
                            const float* __restrict__ attn_w,
                            const float* __restrict__ attn_b,
                            const float* __restrict__ enc,
                            float* __restrict__ hp,
                            unsigned short* __restrict__ Bp,
                            unsigned short* __restrict__ encT16,
                            float* __restrict__ scores,
                            float* __restrict__ ctx) {
  int bid = blockIdx.x, tid = threadIdx.x;
  if (bid < 64) {                      // ---- hidproj ----
    int hl = tid >> 4;                 // 0..15
    int kp = tid & 15;                 // 16-way k-split
    int h  = bid * 16 + hl;
    const f32x4* wrow = (const f32x4*)(attn_w + (size_t)h * (2 * H_DIM)) + kp * 16;
    f32x4 w[16];
#pragma unroll
    for (int j = 0; j < 16; ++j) w[j] = wrow[j];
    float bias = attn_b[h];
    for (int b = 0; b < B_DIM; ++b) {
      const f32x4* xrow = (const f32x4*)(hidden + (size_t)b * H_DIM) + kp * 16;
      float s = 0.f;
#pragma unroll
      for (int j = 0; j < 16; ++j) {
        f32x4 x = xrow[j];
        s = fmaf(w[j].x, x.x, s); s = fmaf(w[j].y, x.y, s);
        s = fmaf(w[j].z, x.z, s); s = fmaf(w[j].w, x.w, s);
      }
      s += __shfl_xor(s, 1); s += __shfl_xor(s, 2);
      s += __shfl_xor(s, 4); s += __shfl_xor(s, 8);
      if (kp == 0) hp[(size_t)b * H_DIM + h] = s + bias;
    }
  } else if (bid < 576) {              // ---- packW2 ----
    int id   = (bid - 64) * 256 + tid; // global chunk 0..131071
    int p    = id & 7;
    int r    = (id >> 3) & 127;
    int half = (id >> 10) & 1;
    int kt   = (id >> 11) & 15;
    int g    = id >> 15;               // 0..3
    int sub  = p ^ (r & 7);
    int n    = g * 256 + half * 128 + r;
    const float* src = attn_w + (size_t)n * (2 * H_DIM) + H_DIM + kt * 64 + sub * 8;
    f32x4 a = *(const f32x4*)src;
    f32x4 b = *(const f32x4*)(src + 4);
    ushort4 lo, hi;
    lo.x = f16_bits(a.x); lo.y = f16_bits(a.y); lo.z = f16_bits(a.z); lo.w = f16_bits(a.w);
    hi.x = f16_bits(b.x); hi.y = f16_bits(b.y); hi.z = f16_bits(b.z); hi.w = f16_bits(b.w);
    *(ushort4*)(Bp + (size_t)id * 8)     = lo;
    *(ushort4*)(Bp + (size_t)id * 8 + 4) = hi;
  } else if (bid < 640) {              // ---- zero scores (256 KiB) ----
    int idx = (bid - 576) * 256 + tid;
    *(f32x4*)(scores + (size_t)idx * 4) = (f32x4){0.f, 0.f, 0.f, 0.f};
  } else if (bid < 672) {              // ---- zero ctx (128 KiB) ----
    int idx = (bid - 640) * 256 + tid;
    *(f32x4*)(ctx + (size_t)idx * 4) = (f32x4){0.f, 0.f, 0.f, 0.f};
  } else {                             // ---- enc -> fp16 tiled (new path) ----
    int cg  = (bid - 672) * 256 + tid; // global chunk 0..8388607
    int q   = cg & 2047;
    int ktt = (cg >> 11) & 15;
    int tt  = cg >> 15;                // 0..255
    int r   = q >> 3;
    int p   = q & 7;
    int sub = p ^ (r & 7);
    const float* src = enc + ((size_t)tt * 256 + r) * H_DIM + ktt * 64 + sub * 8;
    f32x4 a = *(const f32x4*)src;
    f32x4 b = *(const f32x4*)(src + 4);
    ushort4 lo, hi;
    lo.x = f16_bits(a.x); lo.y = f16_bits(a.y); lo.z = f16_bits(a.z); lo.w = f16_bits(a.w);
    hi.x = f16_bits(b.x); hi.y = f16_bits(b.y); hi.z = f16_bits(b.z); hi.w = f16_bits(b.w);
    *(ushort4*)(encT16 + (size_t)cg * 8)     = lo;
    *(ushort4*)(encT16 + (size_t)cg * 8 + 4) = hi;
  }
}

// ---- K3 (new): pure m201-style 256x256, BK=64, 8-wave, counted-vmcnt GEMM ----
// Both operands via global_load_lds from pre-swizzled fp16 images. Per K-tile:
// 4 phases {ds_read frags || stage || [counted wait] || bar || lgkm0 ||
// prio1+16 MFMA+prio0 || bar}. Stage stagger (for tile T+1, during T):
//   P0: A quarters l0 (2 loads)   P1: B all (4 loads), VMC(6) retires A.l1(T)
//   P2: A quarters l1 (2 loads)   P3: VMC(2) retires A.l0+B(T+1), keeps A.l1
// Steady-state waits: vmcnt(6) and vmcnt(2) -- never 0 (T4). Every staged
// half gets >=2.5 phases of flight. Zero VALU in the loop.
__global__ __launch_bounds__(512, 2)
void gemm_scores_kernel(const unsigned short* __restrict__ encT16,
                        const unsigned short* __restrict__ Bp,
                        const float* __restrict__ hp,
                        const float* __restrict__ v,
                        float* __restrict__ scores) {
  __shared__ __align__(16) unsigned short Asl[2][16384];  // 2 x 32 KiB
  __shared__ __align__(16) unsigned short Bsl[2][16384];  // 2 x 32 KiB

  const int tid  = threadIdx.x;
  const int lane = tid & 63;
  const int wid  = tid >> 6;       // 0..7
  const int wm   = wid >> 2;       // row half (128 rows)
  const int wn   = wid & 3;        // 64-col slice
  const int m16  = lane & 15;
  const int quad = lane >> 4;
  const int swz  = m16 & 7;

  // XCD-colocating decode: 4 col-tiles (g) of one row panel on one XCD.
  const int bid  = blockIdx.x;
  const int xcd  = bid & 7;
  const int slot = bid >> 3;                // 0..127
  const int t    = xcd * 32 + (slot >> 2);  // row tile 0..255
  const int g    = slot & 3;                // col tile 0..3

  const int c0 = ((0 * 4 + quad) ^ swz) * 8;  // ko=0 chunk slot
  const int c1 = ((1 * 4 + quad) ^ swz) * 8;  // ko=1

  const unsigned short* Abase = encT16 + (size_t)t * 262144;  // 16 kt x 16384
  const unsigned short* Bbase = Bp     + (size_t)g * 262144;

  f32x4 acc[8][4];
#pragma unroll
  for (int i = 0; i < 8; ++i)
#pragma unroll
    for (int j = 0; j < 4; ++j) acc[i][j] = (f32x4){0.f, 0.f, 0.f, 0.f};

  f16x8 af[4][2];
  f16x8 bf[2][2];

#define STAGE_A_L0(KT, DST)                                                    \
  {                                                                            \
    const unsigned short* s_ = Abase + (size_t)(KT)*16384;                     \
    load_lds16(s_ + (size_t)tid * 8,          (DST) + tid * 8);                \
    load_lds16(s_ + (size_t)(1024 + tid) * 8, (DST) + (1024 + tid) * 8);       \
  }
#define STAGE_A_L1(KT, DST)                                                    \
  {                                                                            \
    const unsigned short* s_ = Abase + (size_t)(KT)*16384;                     \
    load_lds16(s_ + (size_t)(512 + tid) * 8,  (DST) + (512 + tid) * 8);        \
    load_lds16(s_ + (size_t)(1536 + tid) * 8, (DST) + (1536 + tid) * 8);       \
  }
#define STAGE_B4(KT, DST)                                                      \
  {                                                                            \
    const unsigned short* s_ = Bbase + (size_t)(KT)*16384;                     \
    load_lds16(s_ + (size_t)tid * 8,          (DST) + tid * 8);                \
    load_lds16(s_ + (size_t)(512 + tid) * 8,  (DST) + (512 + tid) * 8);        \
    load_lds16(s_ + (size_t)(1024 + tid) * 8, (DST) + (1024 + tid) * 8);       \
    load_lds16(s_ + (size_t)(1536 + tid) * 8, (DST) + (1536 + tid) * 8);       \
  }
#define A_READ(MH, SRC)                                                        \
  _Pragma("unroll")                                                            \
  for (int f = 0; f < 4; ++f) {                                                \
    int r_ = wm * 128 + (MH)*64 + f * 16 + m16;                                \
    af[f][0] = *(const f16x8*)((SRC) + r_ * 64 + c0);                          \
    af[f][1] = *(const f16x8*)((SRC) + r_ * 64 + c1);                          \
  }
#define B_READ(NH, SRC)                                                        \
  _Pragma("unroll")                                                            \
  for (int f = 0; f < 2; ++f) {                                                \
    int n_ = wn * 64 + (NH)*32 + f * 16 + m16;                                 \
    bf[f][0] = *(const f16x8*)((SRC) + n_ * 64 + c0);                          \
    bf[f][1] = *(const f16x8*)((SRC) + n_ * 64 + c1);                          \
  }
#define MFMA_Q(MH, NH)                                                         \
  _Pragma("unroll")                                                            \
  for (int mf = 0; mf < 4; ++mf) {                                             \
    _Pragma("unroll")                                                          \
    for (int nf = 0; nf < 2; ++nf) {                                           \
      acc[(MH)*4 + mf][(NH)*2 + nf] = __builtin_amdgcn_mfma_f32_16x16x32_f16(  \
          af[mf][0], bf[nf][0], acc[(MH)*4 + mf][(NH)*2 + nf], 0, 0, 0);       \
      acc[(MH)*4 + mf][(NH)*2 + nf] = __builtin_amdgcn_mfma_f32_16x16x32_f16(  \
          af[mf][1], bf[nf][1], acc[(MH)*4 + mf][(NH)*2 + nf], 0, 0, 0);       \
    }                                                                          \
  }

  // ---- prologue: tile0 staged in steady-state FIFO order --------------------
  STAGE_A_L0(0, &Asl[0][0]);   // 2 in flight
  STAGE_B4(0, &Bsl[0][0]);     // 6
  STAGE_A_L1(0, &Asl[0][0]);   // 8
  VMC(2);                      // retire A.l0(0)+B(0); keep A.l1(0) in flight
  BAR(); SBAR;

#define TILE(CUR, T)                                                           \
  {                                                                            \
    unsigned short* Ac = &Asl[CUR][0];                                         \
    unsigned short* Bc = &Bsl[CUR][0];                                         \
    unsigned short* An = &Asl[(CUR) ^ 1][0];                                   \
    unsigned short* Bn = &Bsl[(CUR) ^ 1][0];                                   \
    const int ktn = ((T) + 1 < 16) ? (T) + 1 : 15; /* T=15: dummy restage */   \
    /* P0: q(mh0,nh0) */                                                       \
    A_READ(0, Ac); B_READ(0, Bc);                                              \
    STAGE_A_L0(ktn, An);                                                       \
    BAR(); LGKM0();                                                            \
    PRIO1; MFMA_Q(0, 0); PRIO0;                                                \
    BAR(); SBAR;                                                               \
    /* P1: q(mh0,nh1) -- reuse af */                                           \
    B_READ(1, Bc);                                                             \
    STAGE_B4(ktn, Bn);                                                         \
    VMC(6); /* retires A.l1(T): rows 64..127 needed at P2 */                   \
    BAR(); LGKM0();                                                            \
    PRIO1; MFMA_Q(0, 1); PRIO0;                                                \
    BAR(); SBAR;                                                               \
    /* P2: q(mh1,nh1) -- reuse bf */                                           \
    A_READ(1, Ac);                                                             \
    STAGE_A_L1(ktn, An);                                                       \
    BAR(); LGKM0();                                                            \
    PRIO1; MFMA_Q(1, 1); PRIO0;                                                \
    BAR(); SBAR;                                                               \
    /* P3: q(mh1,nh0) */                                                       \
    B_READ(0, Bc);                                                             \
    VMC(2); /* retires A.l0(T+1)+B(T+1); keeps A.l1(T+1) in flight */          \
    BAR(); LGKM0();                                                            \
    PRIO1; MFMA_Q(1, 0); PRIO0;                                                \
    BAR(); SBAR;                                                               \
  }

#pragma unroll 1
  for (int tt = 0; tt < 16; tt += 2) {
    TILE(0, tt);
    TILE(1, tt + 1);
  }

  asm volatile("s_waitcnt vmcnt(0)" ::: "memory");  // drain dummy stages
  SBAR;

  // ---- epilogue: energy = tanh(acc + hp); partial score = sum(e*v) ----------
  // C/D: col = lane&15, row = quad*4 + reg.
  const int row0 = t * 256 + wm * 128;
  const int col0 = g * 256 + wn * 64;
#pragma unroll
  for (int a = 0; a < 8; ++a) {
    const int rbase = row0 + (a >> 2) * 64 + (a & 3) * 16 + quad * 4;
#pragma unroll
    for (int reg = 0; reg < 4; ++reg) {
      int row_g = rbase + reg;
      int bb    = row_g & 31;     // row = s*32 + b
      int ss    = row_g >> 5;
      float psum = 0.f;
#pragma unroll
      for (int b2 = 0; b2 < 4; ++b2) {
        int col = col0 + (b2 >> 1) * 32 + (b2 & 1) * 16 + m16;
        float e = acc[a][b2][reg] + hp[bb * H_DIM + col];
        e = fast_tanh(e);
        psum = fmaf(e, v[col], psum);
      }
      psum += __shfl_xor(psum, 1);
      psum += __shfl_xor(psum, 2);
      psum += __shfl_xor(psum, 4);
      psum += __shfl_xor(psum, 8);
      if (m16 == 0) atomicAdd(&scores[bb * S_DIM + ss], psum);
    }
  }
#undef TILE
#undef MFMA_Q
#undef B_READ
#undef A_READ
#undef STAGE_B4
#undef STAGE_A_L1
#undef STAGE_A_L0
}

// ---- K3 fallback (round-2, known-pass): used only if ws too small -----------
__global__ __launch_bounds__(512, 2)
void gemm_scores_fallback(const float* __restrict__ enc,
                          const unsigned short* __restrict__ Bp,
                          const float* __restrict__ hp,
                          const float* __restrict__ v,
                          float* __restrict__ scores) {
  __shared__ __align__(16) unsigned short Asl[2][16384];
  __shared__ __align__(16) unsigned short Bsl[2][16384];
  const int tid  = threadIdx.x;
  const int lane = tid & 63;
  const int wid  = tid >> 6;
  const int wm   = wid >> 2;
  const int wn   = wid & 3;
  const int m16  = lane & 15;
  const int quad = lane >> 4;
  const int swz  = m16 & 7;
  const int bid  = blockIdx.x;
  const int xcd  = bid & 7;
  const int slot = bid >> 3;
  const int t    = xcd * 32 + (slot >> 2);
  const int g    = slot & 3;
  const int c0  = ((0 * 4 + quad) ^ swz) * 8;
  const int c1  = ((1 * 4 + quad) ^ swz) * 8;
  const int rdA = wm * 8192 + m16 * 64;
  const int rdB = (wn >> 1) * 8192 + ((wn & 1) * 64 + m16) * 64;
  const int r0 = tid >> 3;
  const int s0 = (tid & 7) ^ (r0 & 7);
  const int r1 = (512 + tid) >> 3;
  const int s1 = ((512 + tid) & 7) ^ (r1 & 7);
  const int aoff0 = r0 * H_DIM + s0 * 8;
  const int aoff1 = r1 * H_DIM + s1 * 8;
  const float* encT = enc + (size_t)t * 256 * H_DIM;
  const unsigned short* BpG = Bp + (size_t)g * 262144;

  f32x4 acc[8][4];
#pragma unroll
  for (int i = 0; i < 8; ++i)
#pragma unroll
    for (int j = 0; j < 4; ++j) acc[i][j] = (f32x4){0.f, 0.f, 0.f, 0.f};
  f16x8 af[4][2];
  f16x8 bf[2][2];
  f32x4 rh0[4], rh1[4];

#define ISSUE_A(HH, KT, R)                                                     \
  {                                                                            \
    const float* s_ = encT + (size_t)(HH)*131072 + (KT)*64;                    \
    R[0] = gload16(s_ + aoff0);                                                \
    R[1] = gload16(s_ + aoff0 + 4);                                            \
    R[2] = gload16(s_ + aoff1);                                                \
    R[3] = gload16(s_ + aoff1 + 4);                                            \
  }
#define CVT_WRITE(HH, R, DST)                                                  \
  {                                                                            \
    union { f16x8 v8; h16x2 h2[4]; } pk;                                       \
    pk.h2[0] = __builtin_amdgcn_cvt_pkrtz(R[0].x, R[0].y);                     \
    pk.h2[1] = __builtin_amdgcn_cvt_pkrtz(R[0].z, R[0].w);                     \
    pk.h2[2] = __builtin_amdgcn_cvt_pkrtz(R[1].x, R[1].y);                     \
    pk.h2[3] = __builtin_amdgcn_cvt_pkrtz(R[1].z, R[1].w);                     \
    *(f16x8*)((DST) + (HH)*8192 + tid * 8) = pk.v8;                            \
    pk.h2[0] = __builtin_amdgcn_cvt_pkrtz(R[2].x, R[2].y);                     \
    pk.h2[1] = __builtin_amdgcn_cvt_pkrtz(R[2].z, R[2].w);                     \
    pk.h2[2] = __builtin_amdgcn_cvt_pkrtz(R[3].x, R[3].y);                     \
    pk.h2[3] = __builtin_amdgcn_cvt_pkrtz(R[3].z, R[3].w);                     \
    *(f16x8*)((DST) + (HH)*8192 + 4096 + tid * 8) = pk.v8;                     \
  }
#define STAGE_B(HH, KT, DST)                                                   \
  {                                                                            \
    const unsigned short* s_ = BpG + (KT)*16384 + (HH)*8192 + tid * 8;         \
    load_lds16(s_, (DST) + (HH)*8192 + tid * 8);                               \
    load_lds16(s_ + 4096, (DST) + (HH)*8192 + 4096 + tid * 8);                 \
  }
#define A_READF(MH, SRC)                                                       \
  _Pragma("unroll")                                                            \
  for (int f = 0; f < 4; ++f) {                                                \
    af[f][0] = *(const f16x8*)((SRC) + rdA + ((MH)*64 + f * 16) * 64 + c0);    \
    af[f][1] = *(const f16x8*)((SRC) + rdA + ((MH)*64 + f * 16) * 64 + c1);    \
  }
#define B_READF(NH, SRC)                                                       \
  _Pragma("unroll")                                                            \
  for (int f = 0; f < 2; ++f) {                                                \
    bf[f][0] = *(const f16x8*)((SRC) + rdB + ((NH)*32 + f * 16) * 64 + c0);    \
    bf[f][1] = *(const f16x8*)((SRC) + rdB + ((NH)*32 + f * 16) * 64 + c1);    \
  }
#define MFMA_QF(MH, NH)                                                        \
  _Pragma("unroll")                                                            \
  for (int mf = 0; mf < 4; ++mf) {                                             \
    _Pragma("unroll")                                                          \
    for (int nf = 0; nf < 2; ++nf) {                                           \
      acc[(MH)*4 + mf][(NH)*2 + nf] = __builtin_amdgcn_mfma_f32_16x16x32_f16(  \
          af[mf][0], bf[nf][0], acc[(MH)*4 + mf][(NH)*2 + nf], 0, 0, 0);       \
      acc[(MH)*4 + mf][(NH)*2 + nf] = __builtin_amdgcn_mfma_f32_16x16x32_f16(  \
          af[mf][1], bf[nf][1], acc[(MH)*4 + mf][(NH)*2 + nf], 0, 0, 0);       \
    }                                                                          \
  }

  ISSUE_A(0, 0, rh0);
  ISSUE_A(1, 0, rh1);
  STAGE_B(0, 0, &Bsl[0][0]);
  STAGE_B(1, 0, &Bsl[0][0]);
  VMC(8);
  CVT_WRITE(0, rh0, &Asl[0][0]);
  ISSUE_A(0, 1, rh0);
  VMC(8);
  CVT_WRITE(1, rh1, &Asl[0][0]);
  ISSUE_A(1, 1, rh1);
  VMC(8);
  LGKM0();
  BAR(); SBAR;

#define TILEF(CUR, T)                                                          \
  {                                                                            \
    unsigned short* Ac = &Asl[CUR][0];                                         \
    unsigned short* Bc = &Bsl[CUR][0];                                         \
    unsigned short* An = &Asl[(CUR) ^ 1][0];                                   \
    unsigned short* Bn = &Bsl[(CUR) ^ 1][0];                                   \
    const int ktB = ((T) + 1 < 16) ? (T) + 1 : 15;                             \
    const int ktA = ((T) + 2 < 16) ? (T) + 2 : 15;                             \
    A_READF(0, Ac); B_READF(0, Bc);                                            \
    STAGE_B(0, ktB, Bn);                                                       \
    BAR(); LGKM0();                                                            \
    PRIO1; MFMA_QF(0, 0); PRIO0;                                               \
    BAR(); SBAR;                                                               \
    B_READF(1, Bc);                                                            \
    STAGE_B(1, ktB, Bn);                                                       \
    BAR(); LGKM0();                                                            \
    PRIO1; MFMA_QF(0, 1); PRIO0;                                               \
    BAR(); SBAR;                                                               \
    A_READF(1, Ac);                                                            \
    VMC(8);                                                                    \
    CVT_WRITE(0, rh0, An);                                                     \
    ISSUE_A(0, ktA, rh0);                                                      \
    BAR(); LGKM0();                                                            \
    PRIO1; MFMA_QF(1, 1); PRIO0;                                               \
    BAR(); SBAR;                                                               \
    B_READF(0, Bc);                                                            \
    VMC(8);                                                                    \
    CVT_WRITE(1, rh1, An);                                                     \
    ISSUE_A(1, ktA, rh1);                                                      \
    BAR(); LGKM0();                                                            \
    PRIO1; MFMA_QF(1, 0); PRIO0;                                               \
    VMC(8);                                                                    \
    BAR(); SBAR;                                                               \
  }

#pragma unroll 1
  for (int tt = 0; tt < 16; tt += 2) {
    TILEF(0, tt);
    TILEF(1, tt + 1);
  }
  asm volatile("s_waitcnt vmcnt(0)" ::: "memory");
  SBAR;

  const int row0 = t * 256 + wm * 128;
  const int col0 = g * 256 + wn * 64;
#pragma unroll
  for (int a = 0; a < 8; ++a) {
    const int rbase = row0 + (a >> 2) * 64 + (a & 3) * 16 + quad * 4;
#pragma unroll
    for (int reg = 0; reg < 4; ++reg) {
      int row_g = rbase + reg;
      int bb    = row_g & 31;
      int ss    = row_g >> 5;
      float psum = 0.f;
#pragma unroll
      for (int b2 = 0; b2 < 4; ++b2) {
        int col = col0 + (b2 >> 1) * 32 + (b2 & 1) * 16 + m16;
        float e = acc[a][b2][reg] + hp[bb * H_DIM + col];
        e = fast_tanh(e);
        psum = fmaf(e, v[col], psum);
      }
      psum += __shfl_xor(psum, 1);
      psum += __shfl_xor(psum, 2);
      psum += __shfl_xor(psum, 4);
      psum += __shfl_xor(psum, 8);
      if (m16 == 0) atomicAdd(&scores[bb * S_DIM + ss], psum);
    }
  }
#undef TILEF
#undef MFMA_QF
#undef B_READF
#undef A_READF
#undef STAGE_B
#undef CVT_WRITE
#undef ISSUE_A
}

// ---- K4: masked softmax over s per batch row -> attention weights ------------
__global__ void softmax_kernel(const float* __restrict__ scores,
                               const int* __restrict__ lens,
                               float* __restrict__ wout) {
  int b = blockIdx.x, tid = threadIdx.x;
  int len = lens[b];
  float vals[8];
  float m = -3.0e38f;
#pragma unroll
  for (int i = 0; i < 8; ++i) {
    int s = i * 256 + tid;
    float x = scores[b * S_DIM + s];
    vals[i] = (s < len) ? x : -3.0e38f;
    m = fmaxf(m, vals[i]);
  }
#pragma unroll
  for (int off = 32; off > 0; off >>= 1) m = fmaxf(m, __shfl_xor(m, off));
  __shared__ float redm[4], reds[4];
  int wid = tid >> 6, lane = tid & 63;
  if (lane == 0) redm[wid] = m;
  __syncthreads();
  m = fmaxf(fmaxf(redm[0], redm[1]), fmaxf(redm[2], redm[3]));

  float e[8];
  float sum = 0.f;
#pragma unroll
  for (int i = 0; i < 8; ++i) {
    int s = i * 256 + tid;
    e[i] = (s < len) ? __expf(vals[i] - m) : 0.f;
    sum += e[i];
  }
#pragma unroll
  for (int off = 32; off > 0; off >>= 1) sum += __shfl_xor(sum, off);
  if (lane == 0) reds[wid] = sum;
  __syncthreads();
  sum = reds[0] + reds[1] + reds[2] + reds[3];
  float inv = 1.0f / sum;
#pragma unroll
  for (int i = 0; i < 8; ++i)
    wout[b * S_DIM + i * 256 + tid] = e[i] * inv;
}

// ---- K5: context[b][h] = sum_s w[b][s] * enc[s][b][h] ------------------------
__global__ void context_kernel(const float* __restrict__ enc,
                               const float* __restrict__ wts,
                               const int* __restrict__ lens,
                               float* __restrict__ ctx) {
  int sc = blockIdx.x;
  int b  = blockIdx.y;
  int len = lens[b];
  int s0 = sc * 128;
  if (s0 >= len) return;
  int cnt = min(128, len - s0);
  int tid = threadIdx.x;
  f32x4 acc = (f32x4){0.f, 0.f, 0.f, 0.f};
  const float* wrow = wts + (size_t)b * S_DIM + s0;
#pragma unroll 4
  for (int i = 0; i < cnt; ++i) {
    float w = wrow[i];
    f32x4 e = *(const f32x4*)(enc + ((size_t)(s0 + i) * B_DIM + b) * H_DIM + tid * 4);
    acc.x = fmaf(w, e.x, acc.x);
    acc.y = fmaf(w, e.y, acc.y);
    acc.z = fmaf(w, e.z, acc.z);
    acc.w = fmaf(w, e.w, acc.w);
  }
  float* dst = ctx + (size_t)b * H_DIM + tid * 4;
  atomicAdd(dst + 0, acc.x);
  atomicAdd(dst + 1, acc.y);
  atomicAdd(dst + 2, acc.z);
  atomicAdd(dst + 3, acc.w);
}

// ---- launch -----------------------------------------------------------------
extern "C" void kernel_launch(void* const* d_in, const int* in_sizes, int n_in,
                              void* d_out, int out_size, void* d_ws, size_t ws_size,
                              hipStream_t stream) {
  const float* hidden = (const float*)d_in[0];   // (B,H)
  const float* enc    = (const float*)d_in[1];   // (S,B,H)
  const int*   lens   = (const int*)d_in[2];     // (B,)
  const float* attn_w = (const float*)d_in[3];   // (H,2H)
  const float* attn_b = (const float*)d_in[4];   // (H,)
  const float* v      = (const float*)d_in[5];   // (H,)

  float* out_ctx = (float*)d_out;
  float* out_w   = (float*)d_out + B_DIM * H_DIM;

  // ws: scores (256 KiB) | hp (128 KiB) | Bp fp16 (2 MiB) | enc16 tiled (128 MiB)
  char* p = (char*)d_ws;
  float* scores = (float*)p;               p += (size_t)B_DIM * S_DIM * 4;
  float* hp     = (float*)p;               p += (size_t)B_DIM * H_DIM * 4;
  unsigned short* Bp = (unsigned short*)p; p += (size_t)2 * 1024 * 1024;
  unsigned short* enc16 = (unsigned short*)p;

  const size_t need = (size_t)B_DIM * S_DIM * 4 + (size_t)B_DIM * H_DIM * 4 +
                      (size_t)2 * 1024 * 1024 + (size_t)ROWS * H_DIM * 2;

  if (ws_size >= need) {
    // new path: fp16 pre-convert + pure gload_lds GEMM
    hipLaunchKernelGGL(prep_kernel, dim3(672 + 32768), dim3(256), 0, stream,
                       hidden, attn_w, attn_b, enc, hp, Bp, enc16, scores, out_ctx);
    hipLaunchKernelGGL(gemm_scores_kernel, dim3(1024), dim3(512), 0, stream,
                       enc16, Bp, hp, v, scores);
  } else {
    // fallback: round-2 in-kernel conversion path (known-pass)
    hipLaunchKernelGGL(prep_kernel, dim3(672), dim3(256), 0, stream,
                       hidden, attn_w, attn_b, enc, hp, Bp, enc16, scores, out_ctx);
    hipLaunchKernelGGL(gemm_scores_fallback, dim3(1024), dim3(512), 0, stream,
                       enc, Bp, hp, v, scores);
  }
  hipLaunchKernelGGL(softmax_kernel, dim3(B_DIM), dim3(256), 0, stream,
                     scores, lens, out_w);
  hipLaunchKernelGGL(context_kernel, dim3(16, B_DIM), dim3(256), 0, stream,
                     enc, out_w, lens, out_ctx);
}

// Round 5
// 614.501 us; speedup vs baseline: 1.0442x; 1.0442x over previous
//
#include <hip/hip_runtime.h>

// Problem dims (fixed by reference)
#define S_DIM 2048
#define B_DIM 32
#define H_DIM 1024
#define ROWS  (S_DIM * B_DIM)   // 65536 GEMM rows, row = s*32 + b

typedef __attribute__((ext_vector_type(4))) float    f32x4;
typedef __attribute__((ext_vector_type(8))) _Float16 f16x8;
typedef __attribute__((ext_vector_type(2))) __fp16   h16x2;  // cvt_pkrtz result type

// ---- helpers ----------------------------------------------------------------
__device__ __forceinline__ unsigned short f16_bits(float f) {
  union { _Float16 h; unsigned short u; } cv;
  cv.h = (_Float16)f;           // v_cvt_f16_f32, RNE
  return cv.u;
}

// tanh via one v_exp_f32
__device__ __forceinline__ float fast_tanh(float x) {
  x = fminf(15.0f, fmaxf(-15.0f, x));
  float z = __expf(-2.0f * x);
  return (1.0f - z) * __builtin_amdgcn_rcpf(1.0f + z);
}

// async global->LDS, 16B/lane. LDS dest must be wave-uniform base + lane*16.
__device__ __forceinline__ void load_lds16(const void* g, void* l) {
  __builtin_amdgcn_global_load_lds(
      (const __attribute__((address_space(1))) unsigned int*)g,
      (__attribute__((address_space(3))) unsigned int*)l, 16, 0, 0);
}

// inline-asm global load (fallback path only)
__device__ __forceinline__ f32x4 gload16(const float* p) {
  f32x4 r;
  asm volatile("global_load_dwordx4 %0, %1, off" : "=v"(r) : "v"(p) : "memory");
  return r;
}

// inline-asm LDS read: bypasses SIInsertWaitcnts' conservative LDS-DMA
// aliasing (the pass would otherwise insert its own vmcnt drain before any
// plain-C++ ds_read while global_load_lds ops are outstanding, defeating the
// counted-vmcnt schedule). Ordering vs completion is provided by our explicit
// lgkmcnt(0)+sched_barrier(0); volatile-asm relative order keeps the read
// before the wait.
typedef __attribute__((address_space(3))) const unsigned short* lds_cptr;
__device__ __forceinline__ f16x8 dsr128(const unsigned short* p) {
  f16x8 r;
  unsigned off = (unsigned)(unsigned long long)(lds_cptr)p;
  asm volatile("ds_read_b128 %0, %1" : "=v"(r) : "v"(off));
  return r;
}

#define PRIO1 __builtin_amdgcn_s_setprio(1)
#define PRIO0 __builtin_amdgcn_s_setprio(0)
#define SBAR  __builtin_amdgcn_sched_barrier(0)
#define BAR   __builtin_amdgcn_s_barrier
#define VMC(N) do { asm volatile("s_waitcnt vmcnt(" #N ")" ::: "memory"); \
                    __builtin_amdgcn_sched_barrier(0); } while (0)
#define LGKM0() do { asm volatile("s_waitcnt lgkmcnt(0)" ::: "memory"); \
                     __builtin_amdgcn_sched_barrier(0); } while (0)

// ---- K1 (fused prep): hidproj | packW2 | zero scores | zero ctx | enc->fp16 --
// Bp layout: [g=n/256][kt=k/64][2048 chunks of 16B]; chunk q (r=q>>3, p=q&7)
// holds W2[n=g*256+r][k = kt*64 + (p^(r&7))*8 ..+7] fp16 -- the exact linear
// image global_load_lds deposits (pre-swizzled source, linear LDS dest).
// encT16 layout: [t=row/256][kt][2048 chunks], same chunk rule, rows r<256.
__global__ void prep_kernel(const float* __restrict__ hidden,
                            const float* __restrict__ attn_w,
                            const float* __restrict__ attn_b,
                            const float* __restrict__ enc,
                            float* __restrict__ hp,
                            unsigned short* __restrict__ Bp,
                            unsigned short* __restrict__ encT16,
                            float* __restrict__ scores,
                            float* __restrict__ ctx) {
  int bid = blockIdx.x, tid = threadIdx.x;
  if (bid < 64) {                      // ---- hidproj ----
    int hl = tid >> 4;                 // 0..15
    int kp = tid & 15;                 // 16-way k-split
    int h  = bid * 16 + hl;
    const f32x4* wrow = (const f32x4*)(attn_w + (size_t)h * (2 * H_DIM)) + kp * 16;
    f32x4 w[16];
#pragma unroll
    for (int j = 0; j < 16; ++j) w[j] = wrow[j];
    float bias = attn_b[h];
    for (int b = 0; b < B_DIM; ++b) {
      const f32x4* xrow = (const f32x4*)(hidden + (size_t)b * H_DIM) + kp * 16;
      float s = 0.f;
#pragma unroll
      for (int j = 0; j < 16; ++j) {
        f32x4 x = xrow[j];
        s = fmaf(w[j].x, x.x, s); s = fmaf(w[j].y, x.y, s);
        s = fmaf(w[j].z, x.z, s); s = fmaf(w[j].w, x.w, s);
      }
      s += __shfl_xor(s, 1); s += __shfl_xor(s, 2);
      s += __shfl_xor(s, 4); s += __shfl_xor(s, 8);
      if (kp == 0) hp[(size_t)b * H_DIM + h] = s + bias;
    }
  } else if (bid < 576) {              // ---- packW2 ----
    int id   = (bid - 64) * 256 + tid; // global chunk 0..131071
    int p    = id & 7;
    int r    = (id >> 3) & 127;
    int half = (id >> 10) & 1;
    int kt   = (id >> 11) & 15;
    int g    = id >> 15;               // 0..3
    int sub  = p ^ (r & 7);
    int n    = g * 256 + half * 128 + r;
    const float* src = attn_w + (size_t)n * (2 * H_DIM) + H_DIM + kt * 64 + sub * 8;
    f32x4 a = *(const f32x4*)src;
    f32x4 b = *(const f32x4*)(src + 4);
    ushort4 lo, hi;
    lo.x = f16_bits(a.x); lo.y = f16_bits(a.y); lo.z = f16_bits(a.z); lo.w = f16_bits(a.w);
    hi.x = f16_bits(b.x); hi.y = f16_bits(b.y); hi.z = f16_bits(b.z); hi.w = f16_bits(b.w);
    *(ushort4*)(Bp + (size_t)id * 8)     = lo;
    *(ushort4*)(Bp + (size_t)id * 8 + 4) = hi;
  } else if (bid < 640) {              // ---- zero scores (256 KiB) ----
    int idx = (bid - 576) * 256 + tid;
    *(f32x4*)(scores + (size_t)idx * 4) = (f32x4){0.f, 0.f, 0.f, 0.f};
  } else if (bid < 672) {              // ---- zero ctx (128 KiB) ----
    int idx = (bid - 640) * 256 + tid;
    *(f32x4*)(ctx + (size_t)idx * 4) = (f32x4){0.f, 0.f, 0.f, 0.f};
  } else {                             // ---- enc -> fp16 tiled ----
    int cg  = (bid - 672) * 256 + tid; // global chunk 0..8388607
    int q   = cg & 2047;
    int ktt = (cg >> 11) & 15;
    int tt  = cg >> 15;                // 0..255
    int r   = q >> 3;
    int p   = q & 7;
    int sub = p ^ (r & 7);
    const float* src = enc + ((size_t)tt * 256 + r) * H_DIM + ktt * 64 + sub * 8;
    f32x4 a = *(const f32x4*)src;
    f32x4 b = *(const f32x4*)(src + 4);
    ushort4 lo, hi;
    lo.x = f16_bits(a.x); lo.y = f16_bits(a.y); lo.z = f16_bits(a.z); lo.w = f16_bits(a.w);
    hi.x = f16_bits(b.x); hi.y = f16_bits(b.y); hi.z = f16_bits(b.z); hi.w = f16_bits(b.w);
    *(ushort4*)(encT16 + (size_t)cg * 8)     = lo;
    *(ushort4*)(encT16 + (size_t)cg * 8 + 4) = hi;
  }
}

// ---- K3: 256x256-tile, BK=64, 8-wave, counted-vmcnt GEMM ---------------------
// Round-3-verified schedule with the two anti-implicit-wait changes:
// (1) LDS split into 4 distinct __shared__ objects, (2) frag reads are
// inline-asm ds_read_b128 (no MMO for the waitcnt pass to guard).
__global__ __launch_bounds__(512, 2)
void gemm_scores_kernel(const unsigned short* __restrict__ encT16,
                        const unsigned short* __restrict__ Bp,
                        const float* __restrict__ hp,
                        const float* __restrict__ v,
                        float* __restrict__ scores) {
  __shared__ __align__(16) unsigned short As0[16384];  // 32 KiB
  __shared__ __align__(16) unsigned short As1[16384];
  __shared__ __align__(16) unsigned short Bs0[16384];
  __shared__ __align__(16) unsigned short Bs1[16384];

  const int tid  = threadIdx.x;
  const int lane = tid & 63;
  const int wid  = tid >> 6;       // 0..7
  const int wm   = wid >> 2;       // row half (128 rows)
  const int wn   = wid & 3;        // 64-col slice
  const int m16  = lane & 15;
  const int quad = lane >> 4;
  const int swz  = m16 & 7;

  // XCD-colocating decode: 4 col-tiles (g) of one row panel on one XCD.
  const int bid  = blockIdx.x;
  const int xcd  = bid & 7;
  const int slot = bid >> 3;                // 0..127
  const int t    = xcd * 32 + (slot >> 2);  // row tile 0..255
  const int g    = slot & 3;                // col tile 0..3

  const int c0 = ((0 * 4 + quad) ^ swz) * 8;  // ko=0 chunk slot
  const int c1 = ((1 * 4 + quad) ^ swz) * 8;  // ko=1

  const unsigned short* Abase = encT16 + (size_t)t * 262144;  // 16 kt x 16384
  const unsigned short* Bbase = Bp     + (size_t)g * 262144;

  f32x4 acc[8][4];
#pragma unroll
  for (int i = 0; i < 8; ++i)
#pragma unroll
    for (int j = 0; j < 4; ++j) acc[i][j] = (f32x4){0.f, 0.f, 0.f, 0.f};

  f16x8 af[4][2];
  f16x8 bf[2][2];

// l0 = chunks {0..511, 1024..1535} = rows {0..63, 128..191} (MH0 rows of both wm)
// l1 = chunks {512..1023, 1536..2047} = rows {64..127, 192..255} (MH1 rows)
#define STAGE_A_L0(KT, DST)                                                    \
  {                                                                            \
    const unsigned short* s_ = Abase + (size_t)(KT)*16384;                     \
    load_lds16(s_ + (size_t)tid * 8,          (DST) + tid * 8);                \
    load_lds16(s_ + (size_t)(1024 + tid) * 8, (DST) + (1024 + tid) * 8);       \
  }
#define STAGE_A_L1(KT, DST)                                                    \
  {                                                                            \
    const unsigned short* s_ = Abase + (size_t)(KT)*16384;                     \
    load_lds16(s_ + (size_t)(512 + tid) * 8,  (DST) + (512 + tid) * 8);        \
    load_lds16(s_ + (size_t)(1536 + tid) * 8, (DST) + (1536 + tid) * 8);       \
  }
#define STAGE_B4(KT, DST)                                                      \
  {                                                                            \
    const unsigned short* s_ = Bbase + (size_t)(KT)*16384;                     \
    load_lds16(s_ + (size_t)tid * 8,          (DST) + tid * 8);                \
    load_lds16(s_ + (size_t)(512 + tid) * 8,  (DST) + (512 + tid) * 8);        \
    load_lds16(s_ + (size_t)(1024 + tid) * 8, (DST) + (1024 + tid) * 8);       \
    load_lds16(s_ + (size_t)(1536 + tid) * 8, (DST) + (1536 + tid) * 8);       \
  }
#define A_READ(MH, SRC)                                                        \
  _Pragma("unroll")                                                            \
  for (int f = 0; f < 4; ++f) {                                                \
    int r_ = wm * 128 + (MH)*64 + f * 16 + m16;                                \
    af[f][0] = dsr128((SRC) + r_ * 64 + c0);                                   \
    af[f][1] = dsr128((SRC) + r_ * 64 + c1);                                   \
  }
#define B_READ(NH, SRC)                                                        \
  _Pragma("unroll")                                                            \
  for (int f = 0; f < 2; ++f) {                                                \
    int n_ = wn * 64 + (NH)*32 + f * 16 + m16;                                 \
    bf[f][0] = dsr128((SRC) + n_ * 64 + c0);                                   \
    bf[f][1] = dsr128((SRC) + n_ * 64 + c1);                                   \
  }
#define MFMA_Q(MH, NH)                                                         \
  _Pragma("unroll")                                                            \
  for (int mf = 0; mf < 4; ++mf) {                                             \
    _Pragma("unroll")                                                          \
    for (int nf = 0; nf < 2; ++nf) {                                           \
      acc[(MH)*4 + mf][(NH)*2 + nf] = __builtin_amdgcn_mfma_f32_16x16x32_f16(  \
          af[mf][0], bf[nf][0], acc[(MH)*4 + mf][(NH)*2 + nf], 0, 0, 0);       \
      acc[(MH)*4 + mf][(NH)*2 + nf] = __builtin_amdgcn_mfma_f32_16x16x32_f16(  \
          af[mf][1], bf[nf][1], acc[(MH)*4 + mf][(NH)*2 + nf], 0, 0, 0);       \
    }                                                                          \
  }

  // ---- prologue: tile0 staged in steady-state FIFO order --------------------
  STAGE_A_L0(0, &As0[0]);      // 2 in flight
  STAGE_B4(0, &Bs0[0]);        // 6
  STAGE_A_L1(0, &As0[0]);      // 8
  VMC(2);                      // retire A.l0(0)+B(0); keep A.l1(0) in flight
  BAR(); SBAR;

#define TILE(AC, BC, AN, BN, T)                                                \
  {                                                                            \
    const int ktn = ((T) + 1 < 16) ? (T) + 1 : 15; /* T=15: dummy restage */   \
    /* P0: q(mh0,nh0) */                                                       \
    A_READ(0, AC); B_READ(0, BC);                                              \
    STAGE_A_L0(ktn, AN);                                                       \
    BAR(); LGKM0();                                                            \
    PRIO1; MFMA_Q(0, 0); PRIO0;                                                \
    BAR(); SBAR;                                                               \
    /* P1: q(mh0,nh1) -- reuse af */                                           \
    B_READ(1, BC);                                                             \
    STAGE_B4(ktn, BN);                                                         \
    VMC(6); /* retires A.l1(T): rows 64..127/192..255 needed at P2 */          \
    BAR(); LGKM0();                                                            \
    PRIO1; MFMA_Q(0, 1); PRIO0;                                                \
    BAR(); SBAR;                                                               \
    /* P2: q(mh1,nh1) -- reuse bf */                                           \
    A_READ(1, AC);                                                             \
    STAGE_A_L1(ktn, AN);                                                       \
    BAR(); LGKM0();                                                            \
    PRIO1; MFMA_Q(1, 1); PRIO0;                                                \
    BAR(); SBAR;                                                               \
    /* P3: q(mh1,nh0) */                                                       \
    B_READ(0, BC);                                                             \
    VMC(2); /* retires A.l0(T+1)+B(T+1); keeps A.l1(T+1) in flight */          \
    BAR(); LGKM0();                                                            \
    PRIO1; MFMA_Q(1, 0); PRIO0;                                                \
    BAR(); SBAR;                                                               \
  }

#pragma unroll 1
  for (int tt = 0; tt < 16; tt += 2) {
    TILE(&As0[0], &Bs0[0], &As1[0], &Bs1[0], tt);
    TILE(&As1[0], &Bs1[0], &As0[0], &Bs0[0], tt + 1);
  }

  asm volatile("s_waitcnt vmcnt(0)" ::: "memory");  // drain dummy stages
  SBAR;

  // ---- epilogue: energy = tanh(acc + hp); partial score = sum(e*v) ----------
  // C/D: col = lane&15, row = quad*4 + reg.
  const int row0 = t * 256 + wm * 128;
  const int col0 = g * 256 + wn * 64;
  float vv[4];
#pragma unroll
  for (int b2 = 0; b2 < 4; ++b2)
    vv[b2] = v[col0 + (b2 >> 1) * 32 + (b2 & 1) * 16 + m16];
#pragma unroll
  for (int a = 0; a < 8; ++a) {
    const int rbase = row0 + (a >> 2) * 64 + (a & 3) * 16 + quad * 4;
#pragma unroll
    for (int reg = 0; reg < 4; ++reg) {
      int row_g = rbase + reg;
      int bb    = row_g & 31;     // row = s*32 + b
      int ss    = row_g >> 5;
      float psum = 0.f;
#pragma unroll
      for (int b2 = 0; b2 < 4; ++b2) {
        int col = col0 + (b2 >> 1) * 32 + (b2 & 1) * 16 + m16;
        float e = acc[a][b2][reg] + hp[bb * H_DIM + col];
        e = fast_tanh(e);
        psum = fmaf(e, vv[b2], psum);
      }
      psum += __shfl_xor(psum, 1);
      psum += __shfl_xor(psum, 2);
      psum += __shfl_xor(psum, 4);
      psum += __shfl_xor(psum, 8);
      if (m16 == 0) atomicAdd(&scores[bb * S_DIM + ss], psum);
    }
  }
#undef TILE
#undef MFMA_Q
#undef B_READ
#undef A_READ
#undef STAGE_B4
#undef STAGE_A_L1
#undef STAGE_A_L0
}

// ---- K3 fallback (round-2, known-pass): used only if ws too small -----------
__global__ __launch_bounds__(512, 2)
void gemm_scores_fallback(const float* __restrict__ enc,
                          const unsigned short* __restrict__ Bp,
                          const float* __restrict__ hp,
                          const float* __restrict__ v,
                          float* __restrict__ scores) {
  __shared__ __align__(16) unsigned short Asl[2][16384];
  __shared__ __align__(16) unsigned short Bsl[2][16384];
  const int tid  = threadIdx.x;
  const int lane = tid & 63;
  const int wid  = tid >> 6;
  const int wm   = wid >> 2;
  const int wn   = wid & 3;
  const int m16  = lane & 15;
  const int quad = lane >> 4;
  const int swz  = m16 & 7;
  const int bid  = blockIdx.x;
  const int xcd  = bid & 7;
  const int slot = bid >> 3;
  const int t    = xcd * 32 + (slot >> 2);
  const int g    = slot & 3;
  const int c0  = ((0 * 4 + quad) ^ swz) * 8;
  const int c1  = ((1 * 4 + quad) ^ swz) * 8;
  const int rdA = wm * 8192 + m16 * 64;
  const int rdB = (wn >> 1) * 8192 + ((wn & 1) * 64 + m16) * 64;
  const int r0 = tid >> 3;
  const int s0 = (tid & 7) ^ (r0 & 7);
  const int r1 = (512 + tid) >> 3;
  const int s1 = ((512 + tid) & 7) ^ (r1 & 7);
  const int aoff0 = r0 * H_DIM + s0 * 8;
  const int aoff1 = r1 * H_DIM + s1 * 8;
  const float* encT = enc + (size_t)t * 256 * H_DIM;
  const unsigned short* BpG = Bp + (size_t)g * 262144;

  f32x4 acc[8][4];
#pragma unroll
  for (int i = 0; i < 8; ++i)
#pragma unroll
    for (int j = 0; j < 4; ++j) acc[i][j] = (f32x4){0.f, 0.f, 0.f, 0.f};
  f16x8 af[4][2];
  f16x8 bf[2][2];
  f32x4 rh0[4], rh1[4];

#define ISSUE_A(HH, KT, R)                                                     \
  {                                                                            \
    const float* s_ = encT + (size_t)(HH)*131072 + (KT)*64;                    \
    R[0] = gload16(s_ + aoff0);                                                \
    R[1] = gload16(s_ + aoff0 + 4);                                            \
    R[2] = gload16(s_ + aoff1);                                                \
    R[3] = gload16(s_ + aoff1 + 4);                                            \
  }
#define CVT_WRITE(HH, R, DST)                                                  \
  {                                                                            \
    union { f16x8 v8; h16x2 h2[4]; } pk;                                       \
    pk.h2[0] = __builtin_amdgcn_cvt_pkrtz(R[0].x, R[0].y);                     \
    pk.h2[1] = __builtin_amdgcn_cvt_pkrtz(R[0].z, R[0].w);                     \
    pk.h2[2] = __builtin_amdgcn_cvt_pkrtz(R[1].x, R[1].y);                     \
    pk.h2[3] = __builtin_amdgcn_cvt_pkrtz(R[1].z, R[1].w);                     \
    *(f16x8*)((DST) + (HH)*8192 + tid * 8) = pk.v8;                            \
    pk.h2[0] = __builtin_amdgcn_cvt_pkrtz(R[2].x, R[2].y);                     \
    pk.h2[1] = __builtin_amdgcn_cvt_pkrtz(R[2].z, R[2].w);                     \
    pk.h2[2] = __builtin_amdgcn_cvt_pkrtz(R[3].x, R[3].y);                     \
    pk.h2[3] = __builtin_amdgcn_cvt_pkrtz(R[3].z, R[3].w);                     \
    *(f16x8*)((DST) + (HH)*8192 + 4096 + tid * 8) = pk.v8;                     \
  }
#define STAGE_B(HH, KT, DST)                                                   \
  {                                                                            \
    const unsigned short* s_ = BpG + (KT)*16384 + (HH)*8192 + tid * 8;         \
    load_lds16(s_, (DST) + (HH)*8192 + tid * 8);                               \
    load_lds16(s_ + 4096, (DST) + (HH)*8192 + 4096 + tid * 8);                 \
  }
#define A_READF(MH, SRC)                                                       \
  _Pragma("unroll")                                                            \
  for (int f = 0; f < 4; ++f) {                                                \
    af[f][0] = *(const f16x8*)((SRC) + rdA + ((MH)*64 + f * 16) * 64 + c0);    \
    af[f][1] = *(const f16x8*)((SRC) + rdA + ((MH)*64 + f * 16) * 64 + c1);    \
  }
#define B_READF(NH, SRC)                                                       \
  _Pragma("unroll")                                                            \
  for (int f = 0; f < 2; ++f) {                                                \
    bf[f][0] = *(const f16x8*)((SRC) + rdB + ((NH)*32 + f * 16) * 64 + c0);    \
    bf[f][1] = *(const f16x8*)((SRC) + rdB + ((NH)*32 + f * 16) * 64 + c1);    \
  }
#define MFMA_QF(MH, NH)                                                        \
  _Pragma("unroll")                                                            \
  for (int mf = 0; mf < 4; ++mf) {                                             \
    _Pragma("unroll")                                                          \
    for (int nf = 0; nf < 2; ++nf) {                                           \
      acc[(MH)*4 + mf][(NH)*2 + nf] = __builtin_amdgcn_mfma_f32_16x16x32_f16(  \
          af[mf][0], bf[nf][0], acc[(MH)*4 + mf][(NH)*2 + nf], 0, 0, 0);       \
      acc[(MH)*4 + mf][(NH)*2 + nf] = __builtin_amdgcn_mfma_f32_16x16x32_f16(  \
          af[mf][1], bf[nf][1], acc[(MH)*4 + mf][(NH)*2 + nf], 0, 0, 0);       \
    }                                                                          \
  }

  ISSUE_A(0, 0, rh0);
  ISSUE_A(1, 0, rh1);
  STAGE_B(0, 0, &Bsl[0][0]);
  STAGE_B(1, 0, &Bsl[0][0]);
  VMC(8);
  CVT_WRITE(0, rh0, &Asl[0][0]);
  ISSUE_A(0, 1, rh0);
  VMC(8);
  CVT_WRITE(1, rh1, &Asl[0][0]);
  ISSUE_A(1, 1, rh1);
  VMC(8);
  LGKM0();
  BAR(); SBAR;

#define TILEF(CUR, T)                                                          \
  {                                                                            \
    unsigned short* Ac = &Asl[CUR][0];                                         \
    unsigned short* Bc = &Bsl[CUR][0];                                         \
    unsigned short* An = &Asl[(CUR) ^ 1][0];                                   \
    unsigned short* Bn = &Bsl[(CUR) ^ 1][0];                                   \
    const int ktB = ((T) + 1 < 16) ? (T) + 1 : 15;                             \
    const int ktA = ((T) + 2 < 16) ? (T) + 2 : 15;                             \
    A_READF(0, Ac); B_READF(0, Bc);                                            \
    STAGE_B(0, ktB, Bn);                                                       \
    BAR(); LGKM0();                                                            \
    PRIO1; MFMA_QF(0, 0); PRIO0;                                               \
    BAR(); SBAR;                                                               \
    B_READF(1, Bc);                                                            \
    STAGE_B(1, ktB, Bn);                                                       \
    BAR(); LGKM0();                                                            \
    PRIO1; MFMA_QF(0, 1); PRIO0;                                               \
    BAR(); SBAR;                                                               \
    A_READF(1, Ac);                                                            \
    VMC(8);                                                                    \
    CVT_WRITE(0, rh0, An);                                                     \
    ISSUE_A(0, ktA, rh0);                                                      \
    BAR(); LGKM0();                                                            \
    PRIO1; MFMA_QF(1, 1); PRIO0;                                               \
    BAR(); SBAR;                                                               \
    B_READF(0, Bc);                                                            \
    VMC(8);                                                                    \
    CVT_WRITE(1, rh1, An);                                                     \
    ISSUE_A(1, ktA, rh1);                                                      \
    BAR(); LGKM0();                                                            \
    PRIO1; MFMA_QF(1, 0); PRIO0;                                               \
    VMC(8);                                                                    \
    BAR(); SBAR;                                                               \
  }

#pragma unroll 1
  for (int tt = 0; tt < 16; tt += 2) {
    TILEF(0, tt);
    TILEF(1, tt + 1);
  }
  asm volatile("s_waitcnt vmcnt(0)" ::: "memory");
  SBAR;

  const int row0 = t * 256 + wm * 128;
  const int col0 = g * 256 + wn * 64;
#pragma unroll
  for (int a = 0; a < 8; ++a) {
    const int rbase = row0 + (a >> 2) * 64 + (a & 3) * 16 + quad * 4;
#pragma unroll
    for (int reg = 0; reg < 4; ++reg) {
      int row_g = rbase + reg;
      int bb    = row_g & 31;
      int ss    = row_g >> 5;
      float psum = 0.f;
#pragma unroll
      for (int b2 = 0; b2 < 4; ++b2) {
        int col = col0 + (b2 >> 1) * 32 + (b2 & 1) * 16 + m16;
        float e = acc[a][b2][reg] + hp[bb * H_DIM + col];
        e = fast_tanh(e);
        psum = fmaf(e, v[col], psum);
      }
      psum += __shfl_xor(psum, 1);
      psum += __shfl_xor(psum, 2);
      psum += __shfl_xor(psum, 4);
      psum += __shfl_xor(psum, 8);
      if (m16 == 0) atomicAdd(&scores[bb * S_DIM + ss], psum);
    }
  }
#undef TILEF
#undef MFMA_QF
#undef B_READF
#undef A_READF
#undef STAGE_B
#undef CVT_WRITE
#undef ISSUE_A
}

// ---- K4: masked softmax over s per batch row -> attention weights ------------
__global__ void softmax_kernel(const float* __restrict__ scores,
                               const int* __restrict__ lens,
                               float* __restrict__ wout) {
  int b = blockIdx.x, tid = threadIdx.x;
  int len = lens[b];
  float vals[8];
  float m = -3.0e38f;
#pragma unroll
  for (int i = 0; i < 8; ++i) {
    int s = i * 256 + tid;
    float x = scores[b * S_DIM + s];
    vals[i] = (s < len) ? x : -3.0e38f;
    m = fmaxf(m, vals[i]);
  }
#pragma unroll
  for (int off = 32; off > 0; off >>= 1) m = fmaxf(m, __shfl_xor(m, off));
  __shared__ float redm[4], reds[4];
  int wid = tid >> 6, lane = tid & 63;
  if (lane == 0) redm[wid] = m;
  __syncthreads();
  m = fmaxf(fmaxf(redm[0], redm[1]), fmaxf(redm[2], redm[3]));

  float e[8];
  float sum = 0.f;
#pragma unroll
  for (int i = 0; i < 8; ++i) {
    int s = i * 256 + tid;
    e[i] = (s < len) ? __expf(vals[i] - m) : 0.f;
    sum += e[i];
  }
#pragma unroll
  for (int off = 32; off > 0; off >>= 1) sum += __shfl_xor(sum, off);
  if (lane == 0) reds[wid] = sum;
  __syncthreads();
  sum = reds[0] + reds[1] + reds[2] + reds[3];
  float inv = 1.0f / sum;
#pragma unroll
  for (int i = 0; i < 8; ++i)
    wout[b * S_DIM + i * 256 + tid] = e[i] * inv;
}

// ---- K5: context[b][h] = sum_s w[b][s] * enc[s][b][h] ------------------------
// 32 s-chunks x 32 b = 1024 blocks (4/CU resident) for deeper latency hiding.
__global__ void context_kernel(const float* __restrict__ enc,
                               const float* __restrict__ wts,
                               const int* __restrict__ lens,
                               float* __restrict__ ctx) {
  int sc = blockIdx.x;            // 0..31, 64 s each
  int b  = blockIdx.y;
  int len = lens[b];
  int s0 = sc * 64;
  if (s0 >= len) return;
  int cnt = min(64, len - s0);
  int tid = threadIdx.x;
  f32x4 acc = (f32x4){0.f, 0.f, 0.f, 0.f};
  const float* wrow = wts + (size_t)b * S_DIM + s0;
#pragma unroll 8
  for (int i = 0; i < cnt; ++i) {
    float w = wrow[i];
    f32x4 e = *(const f32x4*)(enc + ((size_t)(s0 + i) * B_DIM + b) * H_DIM + tid * 4);
    acc.x = fmaf(w, e.x, acc.x);
    acc.y = fmaf(w, e.y, acc.y);
    acc.z = fmaf(w, e.z, acc.z);
    acc.w = fmaf(w, e.w, acc.w);
  }
  float* dst = ctx + (size_t)b * H_DIM + tid * 4;
  atomicAdd(dst + 0, acc.x);
  atomicAdd(dst + 1, acc.y);
  atomicAdd(dst + 2, acc.z);
  atomicAdd(dst + 3, acc.w);
}

// ---- launch -----------------------------------------------------------------
extern "C" void kernel_launch(void* const* d_in, const int* in_sizes, int n_in,
                              void* d_out, int out_size, void* d_ws, size_t ws_size,
                              hipStream_t stream) {
  const float* hidden = (const float*)d_in[0];   // (B,H)
  const float* enc    = (const float*)d_in[1];   // (S,B,H)
  const int*   lens   = (const int*)d_in[2];     // (B,)
  const float* attn_w = (const float*)d_in[3];   // (H,2H)
  const float* attn_b = (const float*)d_in[4];   // (H,)
  const float* v      = (const float*)d_in[5];   // (H,)

  float* out_ctx = (float*)d_out;
  float* out_w   = (float*)d_out + B_DIM * H_DIM;

  // ws: scores (256 KiB) | hp (128 KiB) | Bp fp16 (2 MiB) | enc16 tiled (128 MiB)
  char* p = (char*)d_ws;
  float* scores = (float*)p;               p += (size_t)B_DIM * S_DIM * 4;
  float* hp     = (float*)p;               p += (size_t)B_DIM * H_DIM * 4;
  unsigned short* Bp = (unsigned short*)p; p += (size_t)2 * 1024 * 1024;
  unsigned short* enc16 = (unsigned short*)p;

  const size_t need = (size_t)B_DIM * S_DIM * 4 + (size_t)B_DIM * H_DIM * 4 +
                      (size_t)2 * 1024 * 1024 + (size_t)ROWS * H_DIM * 2;

  if (ws_size >= need) {
    hipLaunchKernelGGL(prep_kernel, dim3(672 + 32768), dim3(256), 0, stream,
                       hidden, attn_w, attn_b, enc, hp, Bp, enc16, scores, out_ctx);
    hipLaunchKernelGGL(gemm_scores_kernel, dim3(1024), dim3(512), 0, stream,
                       enc16, Bp, hp, v, scores);
  } else {
    hipLaunchKernelGGL(prep_kernel, dim3(672), dim3(256), 0, stream,
                       hidden, attn_w, attn_b, enc, hp, Bp, enc16, scores, out_ctx);
    hipLaunchKernelGGL(gemm_scores_fallback, dim3(1024), dim3(512), 0, stream,
                       enc, Bp, hp, v, scores);
  }
  hipLaunchKernelGGL(softmax_kernel, dim3(B_DIM), dim3(256), 0, stream,
                     scores, lens, out_w);
  hipLaunchKernelGGL(context_kernel, dim3(32, B_DIM), dim3(256), 0, stream,
                     enc, out_w, lens, out_ctx);
}

// Round 10
// 611.151 us; speedup vs baseline: 1.0499x; 1.0055x over previous
//
#include <hip/hip_runtime.h>

// Problem dims (fixed by reference)
#define S_DIM 2048
#define B_DIM 32
#define H_DIM 1024
#define ROWS  (S_DIM * B_DIM)   // 65536 GEMM rows, row = s*32 + b

typedef __attribute__((ext_vector_type(4))) float    f32x4;
typedef __attribute__((ext_vector_type(8))) _Float16 f16x8;
typedef __attribute__((ext_vector_type(2))) __fp16   h16x2;  // cvt_pkrtz result type

// ---- helpers ----------------------------------------------------------------
__device__ __forceinline__ unsigned short f16_bits(float f) {
  union { _Float16 h; unsigned short u; } cv;
  cv.h = (_Float16)f;           // v_cvt_f16_f32, RNE
  return cv.u;
}

// tanh via one v_exp_f32
__device__ __forceinline__ float fast_tanh(float x) {
  x = fminf(15.0f, fmaxf(-15.0f, x));
  float z = __expf(-2.0f * x);
  return (1.0f - z) * __builtin_amdgcn_rcpf(1.0f + z);
}

// async global->LDS, 16B/lane. LDS dest must be wave-uniform base + lane*16.
__device__ __forceinline__ void load_lds16(const void* g, void* l) {
  __builtin_amdgcn_global_load_lds(
      (const __attribute__((address_space(1))) unsigned int*)g,
      (__attribute__((address_space(3))) unsigned int*)l, 16, 0, 0);
}

// inline-asm global load (fallback path only)
__device__ __forceinline__ f32x4 gload16(const float* p) {
  f32x4 r;
  asm volatile("global_load_dwordx4 %0, %1, off" : "=v"(r) : "v"(p) : "memory");
  return r;
}

// inline-asm LDS read: bypasses SIInsertWaitcnts' conservative LDS-DMA
// aliasing (would insert its own vmcnt drain before plain ds_read while
// global_load_lds ops are outstanding). Ordering vs completion is provided by
// explicit lgkmcnt(0)+sched_barrier(0).
typedef __attribute__((address_space(3))) const unsigned short* lds_cptr;
__device__ __forceinline__ f16x8 dsr128(const unsigned short* p) {
  f16x8 r;
  unsigned off = (unsigned)(unsigned long long)(lds_cptr)p;
  asm volatile("ds_read_b128 %0, %1" : "=v"(r) : "v"(off));
  return r;
}

#define PRIO1 __builtin_amdgcn_s_setprio(1)
#define PRIO0 __builtin_amdgcn_s_setprio(0)
#define SBAR  __builtin_amdgcn_sched_barrier(0)
#define BAR   __builtin_amdgcn_s_barrier
#define VMC(N) do { asm volatile("s_waitcnt vmcnt(" #N ")" ::: "memory"); \
                    __builtin_amdgcn_sched_barrier(0); } while (0)
#define LGKM0() do { asm volatile("s_waitcnt lgkmcnt(0)" ::: "memory"); \
                     __builtin_amdgcn_sched_barrier(0); } while (0)

// ---- K1 (fused prep): hidproj | packW2 | zero scores | zero ctx | enc->fp16 --
// Bp layout: [g=n/256][kt=k/64][2048 chunks of 16B]; chunk q (r=q>>3, p=q&7)
// holds W2[n=g*256+r][k = kt*64 + (p^(r&7))*8 ..+7] fp16 -- the exact linear
// image global_load_lds deposits (pre-swizzled source, linear LDS dest).
// encT16 layout: [t=row/256][kt][2048 chunks], same chunk rule, rows r<256.
__global__ void prep_kernel(const float* __restrict__ hidden,
                            const float* __restrict__ attn_w,
                            const float* __restrict__ attn_b,
                            const float* __restrict__ enc,
                            float* __restrict__ hp,
                            unsigned short* __restrict__ Bp,
                            unsigned short* __restrict__ encT16,
                            float* __restrict__ scores,
                            float* __restrict__ ctx) {
  int bid = blockIdx.x, tid = threadIdx.x;
  if (bid < 64) {                      // ---- hidproj ----
    int hl = tid >> 4;                 // 0..15
    int kp = tid & 15;                 // 16-way k-split
    int h  = bid * 16 + hl;
    const f32x4* wrow = (const f32x4*)(attn_w + (size_t)h * (2 * H_DIM)) + kp * 16;
    f32x4 w[16];
#pragma unroll
    for (int j = 0; j < 16; ++j) w[j] = wrow[j];
    float bias = attn_b[h];
    for (int b = 0; b < B_DIM; ++b) {
      const f32x4* xrow = (const f32x4*)(hidden + (size_t)b * H_DIM) + kp * 16;
      float s = 0.f;
#pragma unroll
      for (int j = 0; j < 16; ++j) {
        f32x4 x = xrow[j];
        s = fmaf(w[j].x, x.x, s); s = fmaf(w[j].y, x.y, s);
        s = fmaf(w[j].z, x.z, s); s = fmaf(w[j].w, x.w, s);
      }
      s += __shfl_xor(s, 1); s += __shfl_xor(s, 2);
      s += __shfl_xor(s, 4); s += __shfl_xor(s, 8);
      if (kp == 0) hp[(size_t)b * H_DIM + h] = s + bias;
    }
  } else if (bid < 576) {              // ---- packW2 ----
    int id   = (bid - 64) * 256 + tid; // global chunk 0..131071
    int p    = id & 7;
    int r    = (id >> 3) & 127;
    int half = (id >> 10) & 1;
    int kt   = (id >> 11) & 15;
    int g    = id >> 15;               // 0..3
    int sub  = p ^ (r & 7);
    int n    = g * 256 + half * 128 + r;
    const float* src = attn_w + (size_t)n * (2 * H_DIM) + H_DIM + kt * 64 + sub * 8;
    f32x4 a = *(const f32x4*)src;
    f32x4 b = *(const f32x4*)(src + 4);
    ushort4 lo, hi;
    lo.x = f16_bits(a.x); lo.y = f16_bits(a.y); lo.z = f16_bits(a.z); lo.w = f16_bits(a.w);
    hi.x = f16_bits(b.x); hi.y = f16_bits(b.y); hi.z = f16_bits(b.z); hi.w = f16_bits(b.w);
    *(ushort4*)(Bp + (size_t)id * 8)     = lo;
    *(ushort4*)(Bp + (size_t)id * 8 + 4) = hi;
  } else if (bid < 640) {              // ---- zero scores (256 KiB) ----
    int idx = (bid - 576) * 256 + tid;
    *(f32x4*)(scores + (size_t)idx * 4) = (f32x4){0.f, 0.f, 0.f, 0.f};
  } else if (bid < 672) {              // ---- zero ctx (128 KiB) ----
    int idx = (bid - 640) * 256 + tid;
    *(f32x4*)(ctx + (size_t)idx * 4) = (f32x4){0.f, 0.f, 0.f, 0.f};
  } else {                             // ---- enc -> fp16 tiled ----
    int cg  = (bid - 672) * 256 + tid; // global chunk 0..8388607
    int q   = cg & 2047;
    int ktt = (cg >> 11) & 15;
    int tt  = cg >> 15;                // 0..255
    int r   = q >> 3;
    int p   = q & 7;
    int sub = p ^ (r & 7);
    const float* src = enc + ((size_t)tt * 256 + r) * H_DIM + ktt * 64 + sub * 8;
    f32x4 a = *(const f32x4*)src;
    f32x4 b = *(const f32x4*)(src + 4);
    ushort4 lo, hi;
    lo.x = f16_bits(a.x); lo.y = f16_bits(a.y); lo.z = f16_bits(a.z); lo.w = f16_bits(a.w);
    hi.x = f16_bits(b.x); hi.y = f16_bits(b.y); hi.z = f16_bits(b.z); hi.w = f16_bits(b.w);
    *(ushort4*)(encT16 + (size_t)cg * 8)     = lo;
    *(ushort4*)(encT16 + (size_t)cg * 8 + 4) = hi;
  }
}

// ---- K3: 256x256-tile, BK=64, 8-wave, counted-vmcnt GEMM ---------------------
// BARRIER THINNING: 2 barriers per K-tile instead of 8. Cross-wave staged-data
// visibility needs a barrier only at the two publishing points -- after VMC(6)
// (publishes A.l1(T), read at P2) and after VMC(2) (publishes A.l0/B(T+1),
// read at next P0). Each wave's own LGKM0 retires its reads-into-regs before
// it reaches those barriers, covering all WAR hazards on the double-buffered
// LDS. Removing the pre/post-MFMA barriers lets the 2 waves/SIMD skew,
// overlapping one wave's ds_read+lgkm latency with the other's MFMA cluster
// (the m201/T5 role-split regime). Per-wave vmcnt ledger: enter tile with 2
// outstanding; P0 +2, P1 +4, VMC(6); P2 +2, VMC(2).
__global__ __launch_bounds__(512, 2)
void gemm_scores_kernel(const unsigned short* __restrict__ encT16,
                        const unsigned short* __restrict__ Bp,
                        const float* __restrict__ hp,
                        const float* __restrict__ v,
                        float* __restrict__ scores) {
  __shared__ __align__(16) unsigned short As0[16384];  // 32 KiB
  __shared__ __align__(16) unsigned short As1[16384];
  __shared__ __align__(16) unsigned short Bs0[16384];
  __shared__ __align__(16) unsigned short Bs1[16384];

  const int tid  = threadIdx.x;
  const int lane = tid & 63;
  const int wid  = tid >> 6;       // 0..7
  const int wm   = wid >> 2;       // row half (128 rows)
  const int wn   = wid & 3;        // 64-col slice
  const int m16  = lane & 15;
  const int quad = lane >> 4;
  const int swz  = m16 & 7;

  // XCD-colocating decode: 4 col-tiles (g) of one row panel on one XCD.
  const int bid  = blockIdx.x;
  const int xcd  = bid & 7;
  const int slot = bid >> 3;                // 0..127
  const int t    = xcd * 32 + (slot >> 2);  // row tile 0..255
  const int g    = slot & 3;                // col tile 0..3

  const int c0 = ((0 * 4 + quad) ^ swz) * 8;  // ko=0 chunk slot
  const int c1 = ((1 * 4 + quad) ^ swz) * 8;  // ko=1

  const unsigned short* Abase = encT16 + (size_t)t * 262144;  // 16 kt x 16384
  const unsigned short* Bbase = Bp     + (size_t)g * 262144;

  f32x4 acc[8][4];
#pragma unroll
  for (int i = 0; i < 8; ++i)
#pragma unroll
    for (int j = 0; j < 4; ++j) acc[i][j] = (f32x4){0.f, 0.f, 0.f, 0.f};

  f16x8 af[4][2];
  f16x8 bf[2][2];

// l0 = chunks {0..511, 1024..1535} = rows {0..63, 128..191} (MH0 rows of both wm)
// l1 = chunks {512..1023, 1536..2047} = rows {64..127, 192..255} (MH1 rows)
#define STAGE_A_L0(KT, DST)                                                    \
  {                                                                            \
    const unsigned short* s_ = Abase + (size_t)(KT)*16384;                     \
    load_lds16(s_ + (size_t)tid * 8,          (DST) + tid * 8);                \
    load_lds16(s_ + (size_t)(1024 + tid) * 8, (DST) + (1024 + tid) * 8);       \
  }
#define STAGE_A_L1(KT, DST)                                                    \
  {                                                                            \
    const unsigned short* s_ = Abase + (size_t)(KT)*16384;                     \
    load_lds16(s_ + (size_t)(512 + tid) * 8,  (DST) + (512 + tid) * 8);        \
    load_lds16(s_ + (size_t)(1536 + tid) * 8, (DST) + (1536 + tid) * 8);       \
  }
#define STAGE_B4(KT, DST)                                                      \
  {                                                                            \
    const unsigned short* s_ = Bbase + (size_t)(KT)*16384;                     \
    load_lds16(s_ + (size_t)tid * 8,          (DST) + tid * 8);                \
    load_lds16(s_ + (size_t)(512 + tid) * 8,  (DST) + (512 + tid) * 8);        \
    load_lds16(s_ + (size_t)(1024 + tid) * 8, (DST) + (1024 + tid) * 8);       \
    load_lds16(s_ + (size_t)(1536 + tid) * 8, (DST) + (1536 + tid) * 8);       \
  }
#define A_READ(MH, SRC)                                                        \
  _Pragma("unroll")                                                            \
  for (int f = 0; f < 4; ++f) {                                                \
    int r_ = wm * 128 + (MH)*64 + f * 16 + m16;                                \
    af[f][0] = dsr128((SRC) + r_ * 64 + c0);                                   \
    af[f][1] = dsr128((SRC) + r_ * 64 + c1);                                   \
  }
#define B_READ(NH, SRC)                                                        \
  _Pragma("unroll")                                                            \
  for (int f = 0; f < 2; ++f) {                                                \
    int n_ = wn * 64 + (NH)*32 + f * 16 + m16;                                 \
    bf[f][0] = dsr128((SRC) + n_ * 64 + c0);                                   \
    bf[f][1] = dsr128((SRC) + n_ * 64 + c1);                                   \
  }
#define MFMA_Q(MH, NH)                                                         \
  _Pragma("unroll")                                                            \
  for (int mf = 0; mf < 4; ++mf) {                                             \
    _Pragma("unroll")                                                          \
    for (int nf = 0; nf < 2; ++nf) {                                           \
      acc[(MH)*4 + mf][(NH)*2 + nf] = __builtin_amdgcn_mfma_f32_16x16x32_f16(  \
          af[mf][0], bf[nf][0], acc[(MH)*4 + mf][(NH)*2 + nf], 0, 0, 0);       \
      acc[(MH)*4 + mf][(NH)*2 + nf] = __builtin_amdgcn_mfma_f32_16x16x32_f16(  \
          af[mf][1], bf[nf][1], acc[(MH)*4 + mf][(NH)*2 + nf], 0, 0, 0);       \
    }                                                                          \
  }

  // ---- prologue: tile0 staged in steady-state FIFO order --------------------
  STAGE_A_L0(0, &As0[0]);      // 2 in flight
  STAGE_B4(0, &Bs0[0]);        // 6
  STAGE_A_L1(0, &As0[0]);      // 8
  VMC(2);                      // retire A.l0(0)+B(0); keep A.l1(0) in flight
  BAR(); SBAR;

#define TILE(AC, BC, AN, BN, T)                                                \
  {                                                                            \
    const int ktn = ((T) + 1 < 16) ? (T) + 1 : 15; /* T=15: dummy restage */   \
    /* P0: q(mh0,nh0) */                                                       \
    A_READ(0, AC); B_READ(0, BC);                                              \
    STAGE_A_L0(ktn, AN);                                                       \
    LGKM0();                                                                   \
    PRIO1; MFMA_Q(0, 0); PRIO0;                                                \
    /* P1: q(mh0,nh1) -- reuse af */                                           \
    B_READ(1, BC);                                                             \
    STAGE_B4(ktn, BN);                                                         \
    LGKM0();                                                                   \
    PRIO1; MFMA_Q(0, 1); PRIO0;                                                \
    VMC(6); /* retires A.l1(T) -- publish for P2 */                            \
    BAR(); SBAR;                                                               \
    /* P2: q(mh1,nh1) -- reuse bf */                                           \
    A_READ(1, AC);                                                             \
    STAGE_A_L1(ktn, AN);                                                       \
    LGKM0();                                                                   \
    PRIO1; MFMA_Q(1, 1); PRIO0;                                                \
    /* P3: q(mh1,nh0) */                                                       \
    B_READ(0, BC);                                                             \
    LGKM0();                                                                   \
    PRIO1; MFMA_Q(1, 0); PRIO0;                                                \
    VMC(2); /* retires A.l0(T+1)+B(T+1) -- publish for next P0 */              \
    BAR(); SBAR;                                                               \
  }

#pragma unroll 1
  for (int tt = 0; tt < 16; tt += 2) {
    TILE(&As0[0], &Bs0[0], &As1[0], &Bs1[0], tt);
    TILE(&As1[0], &Bs1[0], &As0[0], &Bs0[0], tt + 1);
  }

  asm volatile("s_waitcnt vmcnt(0)" ::: "memory");  // drain dummy stages
  SBAR;

  // ---- epilogue: energy = tanh(acc + hp); partial score = sum(e*v) ----------
  // C/D: col = lane&15, row = quad*4 + reg.
  const int row0 = t * 256 + wm * 128;
  const int col0 = g * 256 + wn * 64;
  float vv[4];
#pragma unroll
  for (int b2 = 0; b2 < 4; ++b2)
    vv[b2] = v[col0 + (b2 >> 1) * 32 + (b2 & 1) * 16 + m16];
#pragma unroll
  for (int a = 0; a < 8; ++a) {
    const int rbase = row0 + (a >> 2) * 64 + (a & 3) * 16 + quad * 4;
#pragma unroll
    for (int reg = 0; reg < 4; ++reg) {
      int row_g = rbase + reg;
      int bb    = row_g & 31;     // row = s*32 + b
      int ss    = row_g >> 5;
      float psum = 0.f;
#pragma unroll
      for (int b2 = 0; b2 < 4; ++b2) {
        int col = col0 + (b2 >> 1) * 32 + (b2 & 1) * 16 + m16;
        float e = acc[a][b2][reg] + hp[bb * H_DIM + col];
        e = fast_tanh(e);
        psum = fmaf(e, vv[b2], psum);
      }
      psum += __shfl_xor(psum, 1);
      psum += __shfl_xor(psum, 2);
      psum += __shfl_xor(psum, 4);
      psum += __shfl_xor(psum, 8);
      if (m16 == 0) atomicAdd(&scores[bb * S_DIM + ss], psum);
    }
  }
#undef TILE
#undef MFMA_Q
#undef B_READ
#undef A_READ
#undef STAGE_B4
#undef STAGE_A_L1
#undef STAGE_A_L0
}

// ---- K3 fallback (round-2, known-pass): used only if ws too small -----------
__global__ __launch_bounds__(512, 2)
void gemm_scores_fallback(const float* __restrict__ enc,
                          const unsigned short* __restrict__ Bp,
                          const float* __restrict__ hp,
                          const float* __restrict__ v,
                          float* __restrict__ scores) {
  __shared__ __align__(16) unsigned short Asl[2][16384];
  __shared__ __align__(16) unsigned short Bsl[2][16384];
  const int tid  = threadIdx.x;
  const int lane = tid & 63;
  const int wid  = tid >> 6;
  const int wm   = wid >> 2;
  const int wn   = wid & 3;
  const int m16  = lane & 15;
  const int quad = lane >> 4;
  const int swz  = m16 & 7;
  const int bid  = blockIdx.x;
  const int xcd  = bid & 7;
  const int slot = bid >> 3;
  const int t    = xcd * 32 + (slot >> 2);
  const int g    = slot & 3;
  const int c0  = ((0 * 4 + quad) ^ swz) * 8;
  const int c1  = ((1 * 4 + quad) ^ swz) * 8;
  const int rdA = wm * 8192 + m16 * 64;
  const int rdB = (wn >> 1) * 8192 + ((wn & 1) * 64 + m16) * 64;
  const int r0 = tid >> 3;
  const int s0 = (tid & 7) ^ (r0 & 7);
  const int r1 = (512 + tid) >> 3;
  const int s1 = ((512 + tid) & 7) ^ (r1 & 7);
  const int aoff0 = r0 * H_DIM + s0 * 8;
  const int aoff1 = r1 * H_DIM + s1 * 8;
  const float* encT = enc + (size_t)t * 256 * H_DIM;
  const unsigned short* BpG = Bp + (size_t)g * 262144;

  f32x4 acc[8][4];
#pragma unroll
  for (int i = 0; i < 8; ++i)
#pragma unroll
    for (int j = 0; j < 4; ++j) acc[i][j] = (f32x4){0.f, 0.f, 0.f, 0.f};
  f16x8 af[4][2];
  f16x8 bf[2][2];
  f32x4 rh0[4], rh1[4];

#define ISSUE_A(HH, KT, R)                                                     \
  {                                                                            \
    const float* s_ = encT + (size_t)(HH)*131072 + (KT)*64;                    \
    R[0] = gload16(s_ + aoff0);                                                \
    R[1] = gload16(s_ + aoff0 + 4);                                            \
    R[2] = gload16(s_ + aoff1);                                                \
    R[3] = gload16(s_ + aoff1 + 4);                                            \
  }
#define CVT_WRITE(HH, R, DST)                                                  \
  {                                                                            \
    union { f16x8 v8; h16x2 h2[4]; } pk;                                       \
    pk.h2[0] = __builtin_amdgcn_cvt_pkrtz(R[0].x, R[0].y);                     \
    pk.h2[1] = __builtin_amdgcn_cvt_pkrtz(R[0].z, R[0].w);                     \
    pk.h2[2] = __builtin_amdgcn_cvt_pkrtz(R[1].x, R[1].y);                     \
    pk.h2[3] = __builtin_amdgcn_cvt_pkrtz(R[1].z, R[1].w);                     \
    *(f16x8*)((DST) + (HH)*8192 + tid * 8) = pk.v8;                            \
    pk.h2[0] = __builtin_amdgcn_cvt_pkrtz(R[2].x, R[2].y);                     \
    pk.h2[1] = __builtin_amdgcn_cvt_pkrtz(R[2].z, R[2].w);                     \
    pk.h2[2] = __builtin_amdgcn_cvt_pkrtz(R[3].x, R[3].y);                     \
    pk.h2[3] = __builtin_amdgcn_cvt_pkrtz(R[3].z, R[3].w);                     \
    *(f16x8*)((DST) + (HH)*8192 + 4096 + tid * 8) = pk.v8;                     \
  }
#define STAGE_B(HH, KT, DST)                                                   \
  {                                                                            \
    const unsigned short* s_ = BpG + (KT)*16384 + (HH)*8192 + tid * 8;         \
    load_lds16(s_, (DST) + (HH)*8192 + tid * 8);                               \
    load_lds16(s_ + 4096, (DST) + (HH)*8192 + 4096 + tid * 8);                 \
  }
#define A_READF(MH, SRC)                                                       \
  _Pragma("unroll")                                                            \
  for (int f = 0; f < 4; ++f) {                                                \
    af[f][0] = *(const f16x8*)((SRC) + rdA + ((MH)*64 + f * 16) * 64 + c0);    \
    af[f][1] = *(const f16x8*)((SRC) + rdA + ((MH)*64 + f * 16) * 64 + c1);    \
  }
#define B_READF(NH, SRC)                                                       \
  _Pragma("unroll")                                                            \
  for (int f = 0; f < 2; ++f) {                                                \
    bf[f][0] = *(const f16x8*)((SRC) + rdB + ((NH)*32 + f * 16) * 64 + c0);    \
    bf[f][1] = *(const f16x8*)((SRC) + rdB + ((NH)*32 + f * 16) * 64 + c1);    \
  }
#define MFMA_QF(MH, NH)                                                        \
  _Pragma("unroll")                                                            \
  for (int mf = 0; mf < 4; ++mf) {                                             \
    _Pragma("unroll")                                                          \
    for (int nf = 0; nf < 2; ++nf) {                                           \
      acc[(MH)*4 + mf][(NH)*2 + nf] = __builtin_amdgcn_mfma_f32_16x16x32_f16(  \
          af[mf][0], bf[nf][0], acc[(MH)*4 + mf][(NH)*2 + nf], 0, 0, 0);       \
      acc[(MH)*4 + mf][(NH)*2 + nf] = __builtin_amdgcn_mfma_f32_16x16x32_f16(  \
          af[mf][1], bf[nf][1], acc[(MH)*4 + mf][(NH)*2 + nf], 0, 0, 0);       \
    }                                                                          \
  }

  ISSUE_A(0, 0, rh0);
  ISSUE_A(1, 0, rh1);
  STAGE_B(0, 0, &Bsl[0][0]);
  STAGE_B(1, 0, &Bsl[0][0]);
  VMC(8);
  CVT_WRITE(0, rh0, &Asl[0][0]);
  ISSUE_A(0, 1, rh0);
  VMC(8);
  CVT_WRITE(1, rh1, &Asl[0][0]);
  ISSUE_A(1, 1, rh1);
  VMC(8);
  LGKM0();
  BAR(); SBAR;

#define TILEF(CUR, T)                                                          \
  {                                                                            \
    unsigned short* Ac = &Asl[CUR][0];                                         \
    unsigned short* Bc = &Bsl[CUR][0];                                         \
    unsigned short* An = &Asl[(CUR) ^ 1][0];                                   \
    unsigned short* Bn = &Bsl[(CUR) ^ 1][0];                                   \
    const int ktB = ((T) + 1 < 16) ? (T) + 1 : 15;                             \
    const int ktA = ((T) + 2 < 16) ? (T) + 2 : 15;                             \
    A_READF(0, Ac); B_READF(0, Bc);                                            \
    STAGE_B(0, ktB, Bn);                                                       \
    BAR(); LGKM0();                                                            \
    PRIO1; MFMA_QF(0, 0); PRIO0;                                               \
    BAR(); SBAR;                                                               \
    B_READF(1, Bc);                                                            \
    STAGE_B(1, ktB, Bn);                                                       \
    BAR(); LGKM0();                                                            \
    PRIO1; MFMA_QF(0, 1); PRIO0;                                               \
    BAR(); SBAR;                                                               \
    A_READF(1, Ac);                                                            \
    VMC(8);                                                                    \
    CVT_WRITE(0, rh0, An);                                                     \
    ISSUE_A(0, ktA, rh0);                                                      \
    BAR(); LGKM0();                                                            \
    PRIO1; MFMA_QF(1, 1); PRIO0;                                               \
    BAR(); SBAR;                                                               \
    B_READF(0, Bc);                                                            \
    VMC(8);                                                                    \
    CVT_WRITE(1, rh1, An);                                                     \
    ISSUE_A(1, ktA, rh1);                                                      \
    BAR(); LGKM0();                                                            \
    PRIO1; MFMA_QF(1, 0); PRIO0;                                               \
    VMC(8);                                                                    \
    BAR(); SBAR;                                                               \
  }

#pragma unroll 1
  for (int tt = 0; tt < 16; tt += 2) {
    TILEF(0, tt);
    TILEF(1, tt + 1);
  }
  asm volatile("s_waitcnt vmcnt(0)" ::: "memory");
  SBAR;

  const int row0 = t * 256 + wm * 128;
  const int col0 = g * 256 + wn * 64;
#pragma unroll
  for (int a = 0; a < 8; ++a) {
    const int rbase = row0 + (a >> 2) * 64 + (a & 3) * 16 + quad * 4;
#pragma unroll
    for (int reg = 0; reg < 4; ++reg) {
      int row_g = rbase + reg;
      int bb    = row_g & 31;
      int ss    = row_g >> 5;
      float psum = 0.f;
#pragma unroll
      for (int b2 = 0; b2 < 4; ++b2) {
        int col = col0 + (b2 >> 1) * 32 + (b2 & 1) * 16 + m16;
        float e = acc[a][b2][reg] + hp[bb * H_DIM + col];
        e = fast_tanh(e);
        psum = fmaf(e, v[col], psum);
      }
      psum += __shfl_xor(psum, 1);
      psum += __shfl_xor(psum, 2);
      psum += __shfl_xor(psum, 4);
      psum += __shfl_xor(psum, 8);
      if (m16 == 0) atomicAdd(&scores[bb * S_DIM + ss], psum);
    }
  }
#undef TILEF
#undef MFMA_QF
#undef B_READF
#undef A_READF
#undef STAGE_B
#undef CVT_WRITE
#undef ISSUE_A
}

// ---- K4: masked softmax over s per batch row -> attention weights ------------
__global__ void softmax_kernel(const float* __restrict__ scores,
                               const int* __restrict__ lens,
                               float* __restrict__ wout) {
  int b = blockIdx.x, tid = threadIdx.x;
  int len = lens[b];
  float vals[8];
  float m = -3.0e38f;
#pragma unroll
  for (int i = 0; i < 8; ++i) {
    int s = i * 256 + tid;
    float x = scores[b * S_DIM + s];
    vals[i] = (s < len) ? x : -3.0e38f;
    m = fmaxf(m, vals[i]);
  }
#pragma unroll
  for (int off = 32; off > 0; off >>= 1) m = fmaxf(m, __shfl_xor(m, off));
  __shared__ float redm[4], reds[4];
  int wid = tid >> 6, lane = tid & 63;
  if (lane == 0) redm[wid] = m;
  __syncthreads();
  m = fmaxf(fmaxf(redm[0], redm[1]), fmaxf(redm[2], redm[3]));

  float e[8];
  float sum = 0.f;
#pragma unroll
  for (int i = 0; i < 8; ++i) {
    int s = i * 256 + tid;
    e[i] = (s < len) ? __expf(vals[i] - m) : 0.f;
    sum += e[i];
  }
#pragma unroll
  for (int off = 32; off > 0; off >>= 1) sum += __shfl_xor(sum, off);
  if (lane == 0) reds[wid] = sum;
  __syncthreads();
  sum = reds[0] + reds[1] + reds[2] + reds[3];
  float inv = 1.0f / sum;
#pragma unroll
  for (int i = 0; i < 8; ++i)
    wout[b * S_DIM + i * 256 + tid] = e[i] * inv;
}

// ---- K5: context[b][h] = sum_s w[b][s] * enc[s][b][h] ------------------------
// 32 s-chunks x 32 b = 1024 blocks (4/CU resident) for deeper latency hiding.
__global__ void context_kernel(const float* __restrict__ enc,
                               const float* __restrict__ wts,
                               const int* __restrict__ lens,
                               float* __restrict__ ctx) {
  int sc = blockIdx.x;            // 0..31, 64 s each
  int b  = blockIdx.y;
  int len = lens[b];
  int s0 = sc * 64;
  if (s0 >= len) return;
  int cnt = min(64, len - s0);
  int tid = threadIdx.x;
  f32x4 acc = (f32x4){0.f, 0.f, 0.f, 0.f};
  const float* wrow = wts + (size_t)b * S_DIM + s0;
#pragma unroll 8
  for (int i = 0; i < cnt; ++i) {
    float w = wrow[i];
    f32x4 e = *(const f32x4*)(enc + ((size_t)(s0 + i) * B_DIM + b) * H_DIM + tid * 4);
    acc.x = fmaf(w, e.x, acc.x);
    acc.y = fmaf(w, e.y, acc.y);
    acc.z = fmaf(w, e.z, acc.z);
    acc.w = fmaf(w, e.w, acc.w);
  }
  float* dst = ctx + (size_t)b * H_DIM + tid * 4;
  atomicAdd(dst + 0, acc.x);
  atomicAdd(dst + 1, acc.y);
  atomicAdd(dst + 2, acc.z);
  atomicAdd(dst + 3, acc.w);
}

// ---- launch -----------------------------------------------------------------
extern "C" void kernel_launch(void* const* d_in, const int* in_sizes, int n_in,
                              void* d_out, int out_size, void* d_ws, size_t ws_size,
                              hipStream_t stream) {
  const float* hidden = (const float*)d_in[0];   // (B,H)
  const float* enc    = (const float*)d_in[1];   // (S,B,H)
  const int*   lens   = (const int*)d_in[2];     // (B,)
  const float* attn_w = (const float*)d_in[3];   // (H,2H)
  const float* attn_b = (const float*)d_in[4];   // (H,)
  const float* v      = (const float*)d_in[5];   // (H,)

  float* out_ctx = (float*)d_out;
  float* out_w   = (float*)d_out + B_DIM * H_DIM;

  // ws: scores (256 KiB) | hp (128 KiB) | Bp fp16 (2 MiB) | enc16 tiled (128 MiB)
  char* p = (char*)d_ws;
  float* scores = (float*)p;               p += (size_t)B_DIM * S_DIM * 4;
  float* hp     = (float*)p;               p += (size_t)B_DIM * H_DIM * 4;
  unsigned short* Bp = (unsigned short*)p; p += (size_t)2 * 1024 * 1024;
  unsigned short* enc16 = (unsigned short*)p;

  const size_t need = (size_t)B_DIM * S_DIM * 4 + (size_t)B_DIM * H_DIM * 4 +
                      (size_t)2 * 1024 * 1024 + (size_t)ROWS * H_DIM * 2;

  if (ws_size >= need) {
    hipLaunchKernelGGL(prep_kernel, dim3(672 + 32768), dim3(256), 0, stream,
                       hidden, attn_w, attn_b, enc, hp, Bp, enc16, scores, out_ctx);
    hipLaunchKernelGGL(gemm_scores_kernel, dim3(1024), dim3(512), 0, stream,
                       enc16, Bp, hp, v, scores);
  } else {
    hipLaunchKernelGGL(prep_kernel, dim3(672), dim3(256), 0, stream,
                       hidden, attn_w, attn_b, enc, hp, Bp, enc16, scores, out_ctx);
    hipLaunchKernelGGL(gemm_scores_fallback, dim3(1024), dim3(512), 0, stream,
                       enc, Bp, hp, v, scores);
  }
  hipLaunchKernelGGL(softmax_kernel, dim3(B_DIM), dim3(256), 0, stream,
                     scores, lens, out_w);
  hipLaunchKernelGGL(context_kernel, dim3(32, B_DIM), dim3(256), 0, stream,
                     enc, out_w, lens, out_ctx);
}